// Round 5
// baseline (10151.541 us; speedup 1.0000x reference)
//
#include <hip/hip_runtime.h>

#define NS     4096
#define DDIM   100
#define HD     110
#define JP     128          // padded j stride for weight tiles
#define HP     112          // stats stride
#define TSTEPS 50
#define DTc    0.02f
#define EPSc   1e-6f
#define NB     256
#define BT     512

struct MegaArgs {
  const float *dw, *y_init, *z_init;
  const float *bn0w, *bn0b, *w1, *bn1w, *bn1b, *w2, *bn2w, *bn2b, *w3, *b3, *bn3w, *bn3b;
  float *x, *y, *h1, *h2, *h3;
  float *st0, *st1, *st2, *st3, *lacc;
  float *wt1, *wt2, *wt3, *dwT;
  int *cnt; int usedwt;
  float *out_loss, *out_y, *out_ye, *out_xs, *out_us;
};

// ---------------- grid barrier: arrive (atomicAdd) + spin, device scope ------
__device__ __forceinline__ void gbar(int* cnt, int idx) {
  __syncthreads();
  if (threadIdx.x == 0) {
    __threadfence();                     // release
    atomicAdd(&cnt[idx], 1);
    while (__hip_atomic_load(&cnt[idx], __ATOMIC_RELAXED, __HIP_MEMORY_SCOPE_AGENT) < NB)
      __builtin_amdgcn_s_sleep(1);
    __threadfence();                     // acquire
  }
  __syncthreads();
}

// ---------------- init: weight transpose (+pad) and dw transpose -------------
__device__ void init_phase(const float* __restrict__ w1, const float* __restrict__ w2,
                           const float* __restrict__ w3,
                           float* __restrict__ wt1, float* __restrict__ wt2,
                           float* __restrict__ wt3,
                           const float* __restrict__ dw, float* __restrict__ dwT,
                           int usedwt) {
  int g = blockIdx.x * BT + threadIdx.x;
  for (int idx = g; idx < DDIM * JP; idx += NB * BT) {
    int k = idx >> 7, j = idx & 127;
    wt1[idx] = (j < HD) ? w1[j * DDIM + k] : 0.f;     // w1 [110,100] -> [k][j]
  }
  for (int idx = g; idx < HD * JP; idx += NB * BT) {
    int k = idx >> 7, j = idx & 127;
    wt2[idx] = (j < HD) ? w2[j * HD + k] : 0.f;       // w2 [110,110]
    wt3[idx] = (j < DDIM) ? w3[j * HD + k] : 0.f;     // w3 [100,110]
  }
  if (usedwt) {
    int n = g & (NS - 1);
    int d0 = g >> 12;                                  // 0..31
    for (int d = d0; d < DDIM; d += 32) {
      const float2* src = (const float2*)(dw + (size_t)n * DDIM * TSTEPS + d * TSTEPS);
      float v[TSTEPS];
#pragma unroll
      for (int i = 0; i < TSTEPS / 2; ++i) { float2 p = src[i]; v[2*i] = p.x; v[2*i+1] = p.y; }
#pragma unroll
      for (int tt = 0; tt < TSTEPS; ++tt)
        dwT[((size_t)tt * DDIM + d) * NS + n] = v[tt];  // coalesced over n
    }
  }
}

// ---------------- P0: state update (blocks < 64), + bn0 stats ----------------
template <int LAST>
__device__ void p0_phase(int t, int first, int usedwt,
                         const float* __restrict__ dwT, const float* __restrict__ dwraw,
                         const float* __restrict__ y_init, const float* __restrict__ z_init,
                         const float* __restrict__ bn3w, const float* __restrict__ bn3b,
                         float* __restrict__ x, float* __restrict__ y,
                         const float* __restrict__ h3, const float* __restrict__ st3,
                         float* __restrict__ st0, float* __restrict__ lacc,
                         float* __restrict__ out_y, float* __restrict__ out_ye,
                         float* __restrict__ out_xs, float* __restrict__ out_us,
                         float2* zp, float* ps, float* ush, float* zero_target) {
  int tid = threadIdx.x, lane = tid & 63, w = tid >> 6;
  int bid = blockIdx.x;
  if (bid >= 64) {                                    // idle blocks; block 64 zeroes
    if (bid == 64 && tid < 2 * HP) zero_target[tid] = 0.f;
    return;
  }
  int n = bid * 64 + lane;
  if (!first && tid < DDIM) {
    float m = st3[tid] * (1.f / NS);
    float v = st3[HP + tid] * (1.f / NS) - m * m;
    float istd = rsqrtf(v + EPSc);
    float A = istd * bn3w[tid] * 1e-4f;               // /(DIM*DIM)
    float B = (bn3b[tid] - m * istd * bn3w[tid]) * 1e-4f;
    zp[tid] = make_float2(A, B);
  }
  __syncthreads();
  int d0 = w * 13;
  int cd = DDIM - d0; cd = cd > 13 ? 13 : cd;         // w=7 -> 9
  float xr[13], dwr[13];
  float pz = 0.f, pzdw = 0.f, px2 = 0.f;
#pragma unroll
  for (int i = 0; i < 13; ++i) if (i < cd) {
    int d = d0 + i;
    float zd = first ? z_init[d] : fmaf(h3[(size_t)d * NS + n], zp[d].x, zp[d].y);
    dwr[i] = usedwt ? dwT[((size_t)t * DDIM + d) * NS + n]
                    : dwraw[(size_t)n * DDIM * TSTEPS + d * TSTEPS + t];
    xr[i] = first ? 0.f : x[(size_t)d * NS + n];
    pz += zd; pzdw = fmaf(zd, dwr[i], pzdw); px2 = fmaf(xr[i], xr[i], px2);
  }
  ps[(0 * 8 + w) * 64 + lane] = pz;
  ps[(1 * 8 + w) * 64 + lane] = pzdw;
  ps[(2 * 8 + w) * 64 + lane] = px2;
  __syncthreads();
  if (w == 0) {
    float sz = 0.f, szdw = 0.f, sx2 = 0.f;
#pragma unroll
    for (int k = 0; k < 8; ++k) {
      sz += ps[k * 64 + lane]; szdw += ps[(8 + k) * 64 + lane]; sx2 += ps[(16 + k) * 64 + lane];
    }
    float u = fminf(fmaxf(-sz, -1.f), 1.f);
    float yv = first ? y_init[0] : y[n];
    yv += -DTc * 0.5f * (sx2 + u * u) + DTc * sz * u + szdw;
    out_us[t * NS + n] = u;
    ush[lane] = u;
    if (!LAST) {
      y[n] = yv;
    } else {
      out_y[n] = yv;
      float ye = 0.5f * sx2;
      out_ye[n] = ye;
      float dd = yv - ye, ad = fabsf(dd);
      float s = ad < 1.f ? 0.5f * dd * dd : ad - 0.5f;
      float q = ye;
      for (int off = 32; off; off >>= 1) { s += __shfl_down(s, off); q += __shfl_down(q, off); }
      if (lane == 0) { atomicAdd(&lacc[0], s); atomicAdd(&lacc[1], q); }
    }
  }
  __syncthreads();
  if (!LAST) {
    float u = ush[lane];
#pragma unroll
    for (int i = 0; i < 13; ++i) if (i < cd) {
      int d = d0 + i;
      float xn = fmaf(xr[i], 1.f - DTc, fmaf(u, DTc, dwr[i]));
      x[(size_t)d * NS + n] = xn;
      out_xs[((size_t)t * NS + n) * DDIM + d] = xr[i];   // entry x
      float s = xn, q = xn * xn;
      for (int off = 32; off; off >>= 1) { s += __shfl_down(s, off); q += __shfl_down(q, off); }
      if (lane == 0) { atomicAdd(&st0[d], s); atomicAdd(&st0[HP + d], q); }
    }
  } else {
#pragma unroll
    for (int i = 0; i < 13; ++i) if (i < cd)
      out_xs[((size_t)(TSTEPS - 1) * NS + n) * DDIM + d0 + i] = xr[i];  // final x
  }
}

// ---------------- GEMM phase: bn(+relu) -> matmul -> out + stats -------------
// block = (n-tile of 64) x (j-quarter of 28); wave w<7 owns 4 j; wave 7 idle.
template <int KD, int RELU, int HASB>
__device__ void gemm_phase(const float* __restrict__ in, float* __restrict__ out,
                           const float* __restrict__ stats_in, float* __restrict__ stats_out,
                           const float* __restrict__ bnw, const float* __restrict__ bnb,
                           const float* __restrict__ wt, const float* __restrict__ bias,
                           int Jreal, float* ldsx, float2* ldsab, float* zero_target) {
  int tid = threadIdx.x, lane = tid & 63, w = tid >> 6;
  int n0 = (blockIdx.x & 63) * 64;
  int jq = blockIdx.x >> 6;
  if (tid < KD) {
    float m = stats_in[tid] * (1.f / NS);
    float v = stats_in[HP + tid] * (1.f / NS) - m * m;
    float A = rsqrtf(v + EPSc) * bnw[tid];
    ldsab[tid] = make_float2(A, bnb[tid] - m * A);
  }
  for (int k = w; k < KD; k += 8)                      // stage activation tile
    ldsx[k * 64 + lane] = in[(size_t)k * NS + n0 + lane];
  if (blockIdx.x == 64 && w == 7) {                    // rotate stat-buffer zeroing
    for (int i = lane; i < 2 * HP; i += 64) zero_target[i] = 0.f;
  }
  __syncthreads();
  if (w < 7) {
    int j0 = __builtin_amdgcn_readfirstlane(jq * 28 + w * 4);
    const float* wp = wt + j0;
    float a0 = 0.f, a1 = 0.f, a2 = 0.f, a3 = 0.f;
#pragma unroll 5
    for (int k = 0; k < KD; ++k) {
      float a = ldsx[k * 64 + lane];
      float2 p = ldsab[k];
      a = fmaf(a, p.x, p.y);
      if (RELU) a = fmaxf(a, 0.f);
      const float* wr = wp + k * JP;
      a0 = fmaf(a, wr[0], a0); a1 = fmaf(a, wr[1], a1);
      a2 = fmaf(a, wr[2], a2); a3 = fmaf(a, wr[3], a3);
    }
    float acc[4] = {a0, a1, a2, a3};
#pragma unroll
    for (int i = 0; i < 4; ++i) {
      int j = j0 + i;
      if (j < Jreal) {
        float vv = acc[i] + (HASB ? bias[j] : 0.f);
        out[(size_t)j * NS + n0 + lane] = vv;
        float s = vv, q = vv * vv;
        for (int off = 32; off; off >>= 1) { s += __shfl_down(s, off); q += __shfl_down(q, off); }
        if (lane == 0) { atomicAdd(&stats_out[j], s); atomicAdd(&stats_out[HP + j], q); }
      }
    }
  }
}

// ---------------- the megakernel ---------------------------------------------
__global__ __launch_bounds__(BT, 1) void mega(MegaArgs a) {
  __shared__ float  ldsx[HD * 64];      // 28.2 KB
  __shared__ float2 ldsab[HP];
  __shared__ float2 zp[DDIM];
  __shared__ float  ps[3 * 8 * 64];
  __shared__ float  ush[64];

  init_phase(a.w1, a.w2, a.w3, a.wt1, a.wt2, a.wt3, a.dw, a.dwT, a.usedwt);
  int bi = 0;
  gbar(a.cnt, bi++);

  for (int t = 0; t < TSTEPS - 1; ++t) {
    p0_phase<0>(t, t == 0, a.usedwt, a.dwT, a.dw, a.y_init, a.z_init, a.bn3w, a.bn3b,
                a.x, a.y, a.h3, a.st3, a.st0, a.lacc, a.out_y, a.out_ye, a.out_xs, a.out_us,
                zp, ps, ush, a.st2);
    gbar(a.cnt, bi++);
    gemm_phase<DDIM, 0, 0>(a.x,  a.h1, a.st0, a.st1, a.bn0w, a.bn0b, a.wt1, (const float*)0, HD,   ldsx, ldsab, a.st3);
    gbar(a.cnt, bi++);
    gemm_phase<HD,   1, 0>(a.h1, a.h2, a.st1, a.st2, a.bn1w, a.bn1b, a.wt2, (const float*)0, HD,   ldsx, ldsab, a.st0);
    gbar(a.cnt, bi++);
    gemm_phase<HD,   1, 1>(a.h2, a.h3, a.st2, a.st3, a.bn2w, a.bn2b, a.wt3, a.b3,            DDIM, ldsx, ldsab, a.st1);
    gbar(a.cnt, bi++);
  }
  p0_phase<1>(TSTEPS - 1, 0, a.usedwt, a.dwT, a.dw, a.y_init, a.z_init, a.bn3w, a.bn3b,
              a.x, a.y, a.h3, a.st3, a.st0, a.lacc, a.out_y, a.out_ye, a.out_xs, a.out_us,
              zp, ps, ush, a.st2);
  gbar(a.cnt, bi++);
  if (blockIdx.x == 0 && threadIdx.x == 0) {
    float sl1 = a.lacc[0] * (1.f / NS);
    float mye = a.lacc[1] * (1.f / NS);
    a.out_loss[0] = 100.f * (sl1 + mye * mye);         // 2*DELTA_CLIP = 100
  }
}

extern "C" void kernel_launch(void* const* d_in, const int* in_sizes, int n_in,
                              void* d_out, int out_size, void* d_ws, size_t ws_size,
                              hipStream_t stream) {
  MegaArgs a;
  a.dw     = (const float*)d_in[0];
  a.y_init = (const float*)d_in[1];
  a.z_init = (const float*)d_in[2];
  a.bn0w   = (const float*)d_in[3];
  a.bn0b   = (const float*)d_in[4];
  a.w1     = (const float*)d_in[5];
  a.bn1w   = (const float*)d_in[6];
  a.bn1b   = (const float*)d_in[7];
  a.w2     = (const float*)d_in[8];
  a.bn2w   = (const float*)d_in[9];
  a.bn2b   = (const float*)d_in[10];
  a.w3     = (const float*)d_in[11];
  a.b3     = (const float*)d_in[12];
  a.bn3w   = (const float*)d_in[13];
  a.bn3b   = (const float*)d_in[14];

  float* ws = (float*)d_ws;
  size_t off = 0;
  auto alloc = [&](size_t nf) { float* p = ws + off; off += nf; return p; };
  a.x    = alloc((size_t)DDIM * NS);
  a.y    = alloc(NS);
  a.h1   = alloc((size_t)HP * NS);
  a.h2   = alloc((size_t)HP * NS);
  a.h3   = alloc((size_t)HP * NS);
  a.st0  = alloc(2 * HP);                 // ---- memset region start
  a.st1  = alloc(2 * HP);
  a.st2  = alloc(2 * HP);
  a.st3  = alloc(2 * HP);
  a.lacc = alloc(8);
  a.cnt  = (int*)alloc(256);              // ---- memset region end
  a.wt1  = alloc((size_t)DDIM * JP);
  a.wt2  = alloc((size_t)HD * JP);
  a.wt3  = alloc((size_t)HD * JP);
  a.dwT  = alloc((size_t)TSTEPS * DDIM * NS);   // 82 MB, last
  a.usedwt = (ws_size >= off * sizeof(float)) ? 1 : 0;

  float* out = (float*)d_out;
  a.out_loss = out;
  a.out_y    = out + 1;
  a.out_ye   = a.out_y + NS;
  a.out_xs   = a.out_ye + NS;
  a.out_us   = a.out_xs + (size_t)TSTEPS * NS * DDIM;

  hipMemsetAsync(a.st0, 0, (4 * 2 * HP + 8 + 256) * sizeof(float), stream);
  void* params[] = {&a};
  hipLaunchCooperativeKernel((const void*)mega, dim3(NB), dim3(BT), params, 0, stream);
}